// Round 1
// baseline (34.402 us; speedup 1.0000x reference)
//
#include <hip/hip_runtime.h>

#define NUM_POINTS 2048
#define FEAT 512
#define BATCH 32
#define POS_PER_BLOCK 4

using v8s = __attribute__((ext_vector_type(8))) short;
using v4f = __attribute__((ext_vector_type(4))) float;

// fp32 -> bf16 round-to-nearest-even (inputs are finite normals)
static __device__ __forceinline__ short f2bf(float x) {
  unsigned u = __float_as_uint(x);
  u += 0x7FFFu + ((u >> 16) & 1u);
  return (short)(u >> 16);
}

// Pack glf (fp32 [32 batches][512 feats]) into bf16 MFMA B-fragments in ws.
// Fragment layout for mfma_f32_16x16x32_bf16 B-operand:
//   lane l holds B[k = ks*32 + (l>>4)*8 + j][col = nt*16 + (l&15)], j=0..7
// ws index: (((ks*2 + nt)*64 + l)*8 + j)
__global__ void build_bfrag(const float* __restrict__ glf, short* __restrict__ frag) {
  int i = blockIdx.x * 256 + threadIdx.x;  // 0..16383
  int j = i & 7;
  int l = (i >> 3) & 63;
  int nt = (i >> 9) & 1;
  int ks = i >> 10;
  int b = nt * 16 + (l & 15);
  int k = ks * 32 + ((l >> 4) << 3) + j;
  frag[i] = f2bf(glf[b * FEAT + k]);
}

__global__ void __launch_bounds__(256) fcdec_main(
    const float* __restrict__ W1, const float* __restrict__ b1,
    const float* __restrict__ W2, const float* __restrict__ b2,
    const float* __restrict__ W3, const float* __restrict__ b3,
    const short* __restrict__ bfrag, float* __restrict__ out) {
  // h1s padded to stride 33 to keep epilogue reads conflict-free
  __shared__ float h1s[POS_PER_BLOCK][32][33];
  const int t = threadIdx.x;
  const int w = t >> 6;        // wave id: one position per wave
  const int l = t & 63;
  const int p = blockIdx.x * POS_PER_BLOCK + w;
  const int lrow = l & 15;
  const int lk = (l >> 4) << 3;  // 0,8,16,24

  v4f acc[2][2] = {};
  const float* A0 = W1 + (size_t)p * 32u * FEAT;

  #pragma unroll 4
  for (int ks = 0; ks < 16; ++ks) {
    v8s a[2];
    #pragma unroll
    for (int mt = 0; mt < 2; ++mt) {
      // A-fragment: lane l holds W1row[row = mt*16 + (l&15)][k = ks*32 + (l>>4)*8 + j]
      const float* ap = A0 + (size_t)(mt * 16 + lrow) * FEAT + ks * 32 + lk;
      float4 f0 = *(const float4*)(ap);
      float4 f1 = *(const float4*)(ap + 4);
      v8s av;
      av[0] = f2bf(f0.x); av[1] = f2bf(f0.y); av[2] = f2bf(f0.z); av[3] = f2bf(f0.w);
      av[4] = f2bf(f1.x); av[5] = f2bf(f1.y); av[6] = f2bf(f1.z); av[7] = f2bf(f1.w);
      a[mt] = av;
    }
    #pragma unroll
    for (int nt = 0; nt < 2; ++nt) {
      v8s bv = *(const v8s*)(bfrag + (((ks * 2 + nt) * 64 + l) << 3));
      acc[0][nt] = __builtin_amdgcn_mfma_f32_16x16x32_bf16(a[0], bv, acc[0][nt], 0, 0, 0);
      acc[1][nt] = __builtin_amdgcn_mfma_f32_16x16x32_bf16(a[1], bv, acc[1][nt], 0, 0, 0);
    }
  }

  // Epilogue: h1 = acc + b1 -> LDS.
  // C/D layout: lane l holds C[row = (l>>4)*4 + r][col = l&15]  (m89-verified)
  #pragma unroll
  for (int mt = 0; mt < 2; ++mt)
    #pragma unroll
    for (int nt = 0; nt < 2; ++nt)
      #pragma unroll
      for (int r = 0; r < 4; ++r) {
        int o = mt * 16 + ((l >> 4) << 2) + r;
        int b = nt * 16 + (l & 15);
        h1s[w][o][b] = acc[mt][nt][r] + b1[p * 32 + o];
      }
  __syncthreads();

  // Layers 2+3 in fp32: one thread per (position, batch)
  if (t < POS_PER_BLOCK * 32) {
    int lp = t >> 5;
    int b = t & 31;
    int pg = blockIdx.x * POS_PER_BLOCK + lp;
    float h2[8];
    #pragma unroll
    for (int o8 = 0; o8 < 8; ++o8) {
      float s = b2[pg * 8 + o8];
      const float* w2 = W2 + (size_t)(pg * 8 + o8) * 32;
      #pragma unroll
      for (int i = 0; i < 32; ++i) s += w2[i] * h1s[lp][i][b];
      h2[o8] = s;
    }
    #pragma unroll
    for (int c = 0; c < 3; ++c) {
      float s = b3[pg * 3 + c];
      const float* w3 = W3 + (size_t)(pg * 3 + c) * 8;
      #pragma unroll
      for (int j = 0; j < 8; ++j) s += w3[j] * h2[j];
      out[(size_t)(b * 3 + c) * NUM_POINTS + pg] = s;
    }
  }
}

extern "C" void kernel_launch(void* const* d_in, const int* in_sizes, int n_in,
                              void* d_out, int out_size, void* d_ws, size_t ws_size,
                              hipStream_t stream) {
  const float* glf = (const float*)d_in[0];
  const float* W1  = (const float*)d_in[1];
  const float* b1  = (const float*)d_in[2];
  const float* W2  = (const float*)d_in[3];
  const float* b2  = (const float*)d_in[4];
  const float* W3  = (const float*)d_in[5];
  const float* b3  = (const float*)d_in[6];
  float* out = (float*)d_out;
  short* frag = (short*)d_ws;  // 32 KB of bf16 B-fragments

  hipLaunchKernelGGL(build_bfrag, dim3(64), dim3(256), 0, stream, glf, frag);
  hipLaunchKernelGGL(fcdec_main, dim3(NUM_POINTS / POS_PER_BLOCK), dim3(256), 0, stream,
                     W1, b1, W2, b2, W3, b3, frag, out);
}